// Round 15
// baseline (479.187 us; speedup 1.0000x reference)
//
#include <hip/hip_runtime.h>
#include <math.h>

// R14 measured: 195us/GEMM, MfmaUtil 47.4, nothing saturated (LDS ~50%,
// HBM 20%, L2 10/34 TB/s). 4 sync/memory rounds ~neutral -> binder is the
// MFMA instruction stream: 24x 16x16x32 as 8 chains of 3. R15: switch to
// 32x32x16 MFMA -- same bytes, same tile format, HALF the MFMA instructions
// (12/K-step), +15% shape ceiling (2382 vs 2075 TF). Epilogue remapped to
// 32x32 C/D layout (col=lane&31, row=(reg&3)+8*(reg>>2)+4*(lane>>5)).
// R14 pipeline (3-buf B, counted vmcnt(6), setprio) kept verbatim.

typedef __bf16 bf16;
typedef bf16 bf16x2 __attribute__((ext_vector_type(2)));
typedef bf16 bf16x4 __attribute__((ext_vector_type(4)));
typedef bf16 bf16x8 __attribute__((ext_vector_type(8)));
typedef float f32x4 __attribute__((ext_vector_type(4)));
typedef float f32x16 __attribute__((ext_vector_type(16)));

#define EPS_Q 1e-8f

constexpr int BM = 128, BN = 128, BK = 32;

__device__ __forceinline__ void gload16(const void* g, void* l) {
    __builtin_amdgcn_global_load_lds(
        (const __attribute__((address_space(1))) unsigned int*)g,
        (__attribute__((address_space(3))) unsigned int*)l, 16, 0, 0);
}

// ---------------------------------------------------------------- prep
__global__ __launch_bounds__(256)
void split_ew_tiled(const float* __restrict__ in, bf16* __restrict__ h,
                    bf16* __restrict__ l, int K)
{
    const int t = threadIdx.x;
    #pragma unroll
    for (int i = 0; i < 2; ++i) {
        const int s   = t + i * 256;
        const int row = s >> 2;
        const int kc  = s & 3;
        const float* src = in + (size_t)(blockIdx.y * 128 + row) * K
                              + blockIdx.x * 32 + kc * 8;
        const f32x4 v0 = *reinterpret_cast<const f32x4*>(src);
        const f32x4 v1 = *reinterpret_cast<const f32x4*>(src + 4);
        bf16x8 hh, ll;
        #pragma unroll
        for (int e = 0; e < 4; ++e) {
            const bf16 b0 = (bf16)v0[e];
            hh[e] = b0; ll[e] = (bf16)(v0[e] - (float)b0);
            const bf16 b1 = (bf16)v1[e];
            hh[e + 4] = b1; ll[e + 4] = (bf16)(v1[e] - (float)b1);
        }
        const int slot = row * 4 + ((kc + (row >> 1)) & 3);
        const size_t base = ((size_t)blockIdx.y * gridDim.x + blockIdx.x) * 4096
                          + slot * 8;
        *reinterpret_cast<bf16x8*>(h + base) = hh;
        *reinterpret_cast<bf16x8*>(l + base) = ll;
    }
}

__global__ __launch_bounds__(256)
void split_tr_tiled(const float* __restrict__ in, bf16* __restrict__ h,
                    bf16* __restrict__ l, int Ncols)
{
    const int t = threadIdx.x;
    #pragma unroll
    for (int i = 0; i < 2; ++i) {
        const int s   = t + i * 256;
        const int kc  = s >> 7;
        const int row = s & 127;
        const int sc  = blockIdx.y * 128 + row;
        const int sr  = blockIdx.x * 32 + kc * 8;
        bf16x8 hh, ll;
        #pragma unroll
        for (int j = 0; j < 8; ++j) {
            const float v = in[(size_t)(sr + j) * Ncols + sc];
            const bf16 b = (bf16)v;
            hh[j] = b; ll[j] = (bf16)(v - (float)b);
        }
        const int slot = row * 4 + ((kc + (row >> 1)) & 3);
        const size_t base = ((size_t)blockIdx.y * gridDim.x + blockIdx.x) * 4096
                          + slot * 8;
        *reinterpret_cast<bf16x8*>(h + base) = hh;
        *reinterpret_cast<bf16x8*>(l + base) = ll;
    }
}

// ------------------------------------------------------ pipelined GEMM
#define MFMA32(a,b,c) __builtin_amdgcn_mfma_f32_32x32x16_bf16((a),(b),(c),0,0,0)

// fA[set][0]=h,s0  [1]=h,s1  [2]=l,s0  [3]=l,s1
#define LOAD_A(kt, SET)                                                       \
{   const size_t tb_ = (size_t)(kt) * 8192;                                   \
    fA[SET][0] = *reinterpret_cast<const bf16x8*>(pAh + tb_ + offA[0]);       \
    fA[SET][1] = *reinterpret_cast<const bf16x8*>(pAh + tb_ + offA[1]);       \
    fA[SET][2] = *reinterpret_cast<const bf16x8*>(pAl + tb_ + offA[0]);       \
    fA[SET][3] = *reinterpret_cast<const bf16x8*>(pAl + tb_ + offA[1]); }

#define STAGE_B(kt, BUF)                                                      \
{   const size_t tB_ = (tileB0 + (kt)) * 8192;                                \
    gload16((const char*)Bh_g + tB_ + so, (char*)sBh[BUF] + so);              \
    gload16((const char*)Bl_g + tB_ + so, (char*)sBl[BUF] + so); }

// W: 6 = steady, 4 = tail-1, -1 = last (no barrier)
#define BODY(kt, S, W)                                                        \
{                                                                             \
    if ((kt) + 1 < KT) LOAD_A((kt) + 1, ((S) + 1) % 3);                       \
    __builtin_amdgcn_s_setprio(1);                                            \
    {                                                                         \
        bf16x8 bh00 = *reinterpret_cast<const bf16x8*>((const char*)sBh[(S)] + offB[0]); \
        bf16x8 bh01 = *reinterpret_cast<const bf16x8*>((const char*)sBh[(S)] + offB[1]); \
        bf16x8 bh10 = *reinterpret_cast<const bf16x8*>((const char*)sBh[(S)] + offB[2]); \
        bf16x8 bh11 = *reinterpret_cast<const bf16x8*>((const char*)sBh[(S)] + offB[3]); \
        bf16x8 bl00 = *reinterpret_cast<const bf16x8*>((const char*)sBl[(S)] + offB[0]); \
        bf16x8 bl01 = *reinterpret_cast<const bf16x8*>((const char*)sBl[(S)] + offB[1]); \
        bf16x8 bl10 = *reinterpret_cast<const bf16x8*>((const char*)sBl[(S)] + offB[2]); \
        bf16x8 bl11 = *reinterpret_cast<const bf16x8*>((const char*)sBl[(S)] + offB[3]); \
        /* s=0 : pass-major, c inner (adjacent MFMAs independent) */          \
        acc[0] = MFMA32(fA[(S)][0], bh00, acc[0]);                            \
        acc[1] = MFMA32(fA[(S)][0], bh10, acc[1]);                            \
        acc[0] = MFMA32(fA[(S)][0], bl00, acc[0]);                            \
        acc[1] = MFMA32(fA[(S)][0], bl10, acc[1]);                            \
        acc[0] = MFMA32(fA[(S)][2], bh00, acc[0]);                            \
        acc[1] = MFMA32(fA[(S)][2], bh10, acc[1]);                            \
        /* s=1 */                                                             \
        acc[0] = MFMA32(fA[(S)][1], bh01, acc[0]);                            \
        acc[1] = MFMA32(fA[(S)][1], bh11, acc[1]);                            \
        acc[0] = MFMA32(fA[(S)][1], bl01, acc[0]);                            \
        acc[1] = MFMA32(fA[(S)][1], bl11, acc[1]);                            \
        acc[0] = MFMA32(fA[(S)][3], bh01, acc[0]);                            \
        acc[1] = MFMA32(fA[(S)][3], bh11, acc[1]);                            \
    }                                                                         \
    __builtin_amdgcn_s_setprio(0);                                            \
    if ((W) == 6)      asm volatile("s_waitcnt vmcnt(6)" ::: "memory");       \
    else if ((W) == 4) asm volatile("s_waitcnt vmcnt(4)" ::: "memory");       \
    else if ((W) == 0) asm volatile("s_waitcnt vmcnt(0)" ::: "memory");       \
    if ((W) >= 0) {                                                           \
        __builtin_amdgcn_sched_barrier(0);                                    \
        __builtin_amdgcn_s_barrier();                                         \
        __builtin_amdgcn_sched_barrier(0);                                    \
        if ((kt) + 3 < KT) STAGE_B((kt) + 3, (S));                            \
    }                                                                         \
}

template<int EPI, int KT>
__global__ __launch_bounds__(512, 4)
void qlin_mfma8(const bf16* __restrict__ Ah_g, const bf16* __restrict__ Al_g,
                const bf16* __restrict__ Bh_g, const bf16* __restrict__ Bl_g,
                int M, int N,
                float* __restrict__ Cf, bf16* __restrict__ Ch, bf16* __restrict__ Cl,
                const float* __restrict__ g_lx, const float* __restrict__ g_lw,
                const float* __restrict__ g_dx, const float* __restrict__ g_cb,
                const float* __restrict__ g_rcb, const float* __restrict__ g_bias)
{
    __shared__ __align__(16) bf16 sBh[3][4096], sBl[3][4096];   // 48 KB
    __shared__ float s_cb[16], s_rcb[16], s_mid[15], s_rmid[15];

    const int tid = threadIdx.x;
    const int ln  = tid & 63;
    const int wid = tid >> 6;

    if (EPI == 1) {
        if (tid < 16) { s_cb[tid] = g_cb[tid]; s_rcb[tid] = g_rcb[tid]; }
        __syncthreads();
        if (tid < 15) {
            s_mid[tid]  = 0.5f * (s_cb[tid] + s_cb[tid + 1]);
            s_rmid[tid] = 0.5f * (s_rcb[tid] + s_rcb[tid + 1]);
        }
    }

    const int wm = (wid >> 1) * 32;    // wave row base
    const int wn = (wid & 1) * 64;     // wave col base
    const int l5 = ln >> 5;            // 0/1: which half of k-sub this lane reads
    const int r31 = ln & 31;

    // A fragment offsets: s-th k-sub, 32-row frag. kc = s*2 + l5.
    int offA[2];
    #pragma unroll
    for (int s = 0; s < 2; ++s) {
        const int row = wm + r31;
        const int kc  = s * 2 + l5;
        offA[s] = row * 64 + (((kc + (row >> 1)) & 3) << 4);
    }
    const char* pAh = (const char*)Ah_g + (size_t)blockIdx.y * KT * 8192;
    const char* pAl = (const char*)Al_g + (size_t)blockIdx.y * KT * 8192;

    const size_t tileB0 = (size_t)blockIdx.x * KT;
    const int so = tid << 4;

    // B fragment LDS offsets: offB[c*2+s]
    int offB[4];
    #pragma unroll
    for (int c = 0; c < 2; ++c)
        #pragma unroll
        for (int s = 0; s < 2; ++s) {
            const int row = wn + c * 32 + r31;
            const int kc  = s * 2 + l5;
            offB[c * 2 + s] = row * 64 + (((kc + (row >> 1)) & 3) << 4);
        }

    bf16x8 fA[3][4];
    f32x16 acc[2] = {};

    // prologue: A(0) + B tiles 0,1,2; confirm A0,B0 (leave 4 in flight)
    LOAD_A(0, 0);
    STAGE_B(0, 0);
    STAGE_B(1, 1);
    STAGE_B(2, 2);
    asm volatile("s_waitcnt vmcnt(4)" ::: "memory");
    __builtin_amdgcn_sched_barrier(0);
    __builtin_amdgcn_s_barrier();
    __builtin_amdgcn_sched_barrier(0);

    constexpr int NB   = (KT - 2) % 3;
    constexpr int MAIN = (KT - 2) - NB;
    for (int kt = 0; kt < MAIN; kt += 3) {
        BODY(kt,     0, 6);
        BODY(kt + 1, 1, 6);
        BODY(kt + 2, 2, 6);
    }
    if constexpr (NB >= 1) { BODY(MAIN,     0, 6); }
    if constexpr (NB >= 2) { BODY(MAIN + 1, 1, 6); }
    { constexpr int S1 = (KT - 2) % 3; BODY(KT - 2, S1, 4); }
    { constexpr int S2 = (KT - 1) % 3; BODY(KT - 1, S2, -1); }

    // ---- epilogue (32x32 C/D: col=lane&31, row=(r&3)+8*(r>>2)+4*(lane>>5))
    if (EPI == 1) {
        float mid[15], rmid[15];
        #pragma unroll
        for (int k = 0; k < 15; ++k) { mid[k] = s_mid[k]; rmid[k] = s_rmid[k]; }
        const int NT = N >> 5;
        #pragma unroll
        for (int c = 0; c < 2; ++c) {
            const int cg = blockIdx.x * BN + wn + c * 32 + r31;
            const float lx = g_lx[cg], lw = g_lw[cg], dx = g_dx[cg];
            const float slx = (fabsf(lx) < EPS_Q) ? EPS_Q : lx;
            const float sdx = (fabsf(dx) < EPS_Q) ? EPS_Q : dx;
            const float ilx = 1.0f / slx, isdx = 1.0f / sdx;
            const float c1 = lx * lw, c2 = dx * lw;
            const int tk = cg >> 5, kc = (cg >> 3) & 3, j = cg & 7;
            #pragma unroll
            for (int r = 0; r < 16; ++r) {
                const float p = acc[c][r];
                const float z = p * ilx;
                int i1 = 0;
                #pragma unroll
                for (int k = 0; k < 15; ++k) i1 += (mid[k] < z) ? 1 : 0;
                const float zq = s_cb[i1];
                const float zr = (p - zq * lx) * isdx;
                int i2 = 0;
                #pragma unroll
                for (int k = 0; k < 15; ++k) i2 += (rmid[k] < zr) ? 1 : 0;
                const float qr = s_rcb[i2];
                const float v  = zq * c1 + qr * c2;
                const bf16  vh = (bf16)v;
                const int rowInTile = wm + (r & 3) + 8 * (r >> 2) + 4 * l5;
                const int slot = rowInTile * 4 + ((kc + (rowInTile >> 1)) & 3);
                const size_t o = ((size_t)blockIdx.y * NT + tk) * 4096
                               + slot * 8 + j;
                Ch[o] = vh;
                Cl[o] = (bf16)(v - (float)vh);
            }
        }
    } else {
        #pragma unroll
        for (int c = 0; c < 2; ++c) {
            const int cg = blockIdx.x * BN + wn + c * 32 + r31;
            const float bv = g_bias[cg];
            #pragma unroll
            for (int r = 0; r < 16; ++r) {
                const int row = blockIdx.y * BM + wm + (r & 3) + 8 * (r >> 2) + 4 * l5;
                Cf[(size_t)row * N + cg] = acc[c][r] + bv;
            }
        }
    }
}

// --------------------------------------------- fallback (R7, validated path)
constexpr int FLDK = BK + 8;

__device__ __forceinline__ bf16x8 ld8(const bf16* p) {
    const bf16x4 a = *reinterpret_cast<const bf16x4*>(p);
    const bf16x4 b = *reinterpret_cast<const bf16x4*>(p + 4);
    return __builtin_shufflevector(a, b, 0, 1, 2, 3, 4, 5, 6, 7);
}
#define MFMA_(a,b,c) __builtin_amdgcn_mfma_f32_16x16x32_bf16((a),(b),(c),0,0,0)

template<int EPI>
__global__ __launch_bounds__(256, 2)
void qlin_mfma(const float* __restrict__ A, const float* __restrict__ B,
               float* __restrict__ C, int M, int N, int K,
               const float* __restrict__ g_lx, const float* __restrict__ g_lw,
               const float* __restrict__ g_dx, const float* __restrict__ g_cb,
               const float* __restrict__ g_rcb, const float* __restrict__ g_bias)
{
    __shared__ bf16 Ah[BM][FLDK], Al[BM][FLDK], Bh[BN][FLDK], Bl[BN][FLDK];
    __shared__ float s_cb[16], s_rcb[16], s_mid[15], s_rmid[15];

    const int tid = threadIdx.x;
    const int bm  = blockIdx.y * BM;
    const int bn  = blockIdx.x * BN;

    if (EPI == 1) {
        if (tid < 16) { s_cb[tid] = g_cb[tid]; s_rcb[tid] = g_rcb[tid]; }
        __syncthreads();
        if (tid < 15) {
            s_mid[tid]  = 0.5f * (s_cb[tid] + s_cb[tid + 1]);
            s_rmid[tid] = 0.5f * (s_rcb[tid] + s_rcb[tid + 1]);
        }
    }

    const int am  = tid >> 1;
    const int ak0 = (tid & 1) * 16;
    const int bk  = (tid >> 4) * 2;
    const int bn0 = (tid & 15) * 8;
    const float* Abase = A + (size_t)(bm + am) * K + ak0;

    f32x4 rA[4], rB[4];
    auto LOADREGS = [&](int kt) {
        const float* ap = Abase + (size_t)kt * BK;
        #pragma unroll
        for (int q = 0; q < 4; ++q)
            rA[q] = *reinterpret_cast<const f32x4*>(ap + q * 4);
        #pragma unroll
        for (int q = 0; q < 4; ++q)
            rB[q] = *reinterpret_cast<const f32x4*>(
                B + (size_t)(kt * BK + bk + (q >> 1)) * N + bn + bn0 + (q & 1) * 4);
    };
    auto WRITELDS = [&]() {
        #pragma unroll
        for (int q = 0; q < 4; ++q) {
            bf16x4 h, l;
            #pragma unroll
            for (int e = 0; e < 4; ++e) {
                const float x = rA[q][e];
                const bf16  hh = (bf16)x;
                h[e] = hh;
                l[e] = (bf16)(x - (float)hh);
            }
            *reinterpret_cast<bf16x4*>(&Ah[am][ak0 + q * 4]) = h;
            *reinterpret_cast<bf16x4*>(&Al[am][ak0 + q * 4]) = l;
        }
        const int js = tid & 7;
        #pragma unroll
        for (int jj = 0; jj < 8; ++jj) {
            const int j = (jj + js) & 7;
            const float x0 = rB[(j >> 2)][j & 3];
            const float x1 = rB[2 + (j >> 2)][j & 3];
            const bf16 h0 = (bf16)x0, h1 = (bf16)x1;
            const bf16 l0 = (bf16)(x0 - (float)h0), l1 = (bf16)(x1 - (float)h1);
            bf16x2 ph = {h0, h1}, pl = {l0, l1};
            *reinterpret_cast<bf16x2*>(&Bh[bn0 + j][bk]) = ph;
            *reinterpret_cast<bf16x2*>(&Bl[bn0 + j][bk]) = pl;
        }
    };

    const int ln  = tid & 63;
    const int wid = tid >> 6;
    const int wm  = (wid >> 1) * 64;
    const int wn  = (wid & 1) * 64;
    const int fr  = ln & 15;
    const int k8  = (ln >> 4) * 8;

    f32x4 acc[4][4] = {};
    const int NK = K / BK;
    LOADREGS(0);
    for (int kt = 0; kt < NK; ++kt) {
        __syncthreads();
        WRITELDS();
        __syncthreads();
        if (kt + 1 < NK) LOADREGS(kt + 1);

        bf16x8 fAh[4], fAl[4];
        #pragma unroll
        for (int mi = 0; mi < 4; ++mi) {
            fAh[mi] = ld8(&Ah[wm + mi * 16 + fr][k8]);
            fAl[mi] = ld8(&Al[wm + mi * 16 + fr][k8]);
        }
        #pragma unroll
        for (int nj = 0; nj < 4; ++nj) {
            const bf16x8 fBh = ld8(&Bh[wn + nj * 16 + fr][k8]);
            const bf16x8 fBl = ld8(&Bl[wn + nj * 16 + fr][k8]);
            #pragma unroll
            for (int mi = 0; mi < 4; ++mi) {
                acc[mi][nj] = MFMA_(fAh[mi], fBh, acc[mi][nj]);
                acc[mi][nj] = MFMA_(fAh[mi], fBl, acc[mi][nj]);
                acc[mi][nj] = MFMA_(fAl[mi], fBh, acc[mi][nj]);
            }
        }
    }

    const int rbase = bm + wm + (ln >> 4) * 4;
    if (EPI == 1) {
        float mid[15], rmid[15];
        #pragma unroll
        for (int k = 0; k < 15; ++k) { mid[k] = s_mid[k]; rmid[k] = s_rmid[k]; }
        #pragma unroll
        for (int nj = 0; nj < 4; ++nj) {
            const int c = bn + wn + nj * 16 + fr;
            const float lx = g_lx[c], lw = g_lw[c], dx = g_dx[c];
            const float slx = (fabsf(lx) < EPS_Q) ? EPS_Q : lx;
            const float sdx = (fabsf(dx) < EPS_Q) ? EPS_Q : dx;
            const float ilx = 1.0f / slx, isdx = 1.0f / sdx;
            const float c1 = lx * lw, c2 = dx * lw;
            #pragma unroll
            for (int mi = 0; mi < 4; ++mi)
                #pragma unroll
                for (int r = 0; r < 4; ++r) {
                    const float p = acc[mi][nj][r];
                    const float z = p * ilx;
                    int i1 = 0;
                    #pragma unroll
                    for (int k = 0; k < 15; ++k) i1 += (mid[k] < z) ? 1 : 0;
                    const float zq = s_cb[i1];
                    const float zr = (p - zq * lx) * isdx;
                    int i2 = 0;
                    #pragma unroll
                    for (int k = 0; k < 15; ++k) i2 += (rmid[k] < zr) ? 1 : 0;
                    const float qr = s_rcb[i2];
                    C[(size_t)(rbase + mi * 16 + r) * N + c] = zq * c1 + qr * c2;
                }
        }
    } else {
        #pragma unroll
        for (int nj = 0; nj < 4; ++nj) {
            const int c = bn + wn + nj * 16 + fr;
            const float bv = g_bias[c];
            #pragma unroll
            for (int mi = 0; mi < 4; ++mi)
                #pragma unroll
                for (int r = 0; r < 4; ++r)
                    C[(size_t)(rbase + mi * 16 + r) * N + c] = acc[mi][nj][r] + bv;
        }
    }
}

// ------------------------------------------------------------------- launch
extern "C" void kernel_launch(void* const* d_in, const int* in_sizes, int n_in,
                              void* d_out, int out_size, void* d_ws, size_t ws_size,
                              hipStream_t stream)
{
    const float* X    = (const float*)d_in[0];
    const float* U    = (const float*)d_in[1];
    const float* lx   = (const float*)d_in[2];
    const float* lw   = (const float*)d_in[3];
    const float* Zw   = (const float*)d_in[4];
    const float* cb   = (const float*)d_in[5];
    const float* dx   = (const float*)d_in[6];
    const float* rcb  = (const float*)d_in[7];
    const float* bias = (const float*)d_in[8];
    float* out = (float*)d_out;

    const int R    = in_sizes[2];
    const int DIN  = in_sizes[1] / R;
    const int M    = in_sizes[0] / DIN;
    const int DOUT = in_sizes[8];

    const size_t szX = (size_t)M * DIN * sizeof(bf16);
    const size_t szU = (size_t)DIN * R * sizeof(bf16);
    const size_t szZ = (size_t)R * DOUT * sizeof(bf16);
    const size_t szV = (size_t)M * R * sizeof(bf16);
    const size_t need = 2 * (szX + szU + szZ + szV);

    const int KT1 = DIN / 32;
    const int KT2 = R / 32;

    if (ws_size >= need && KT1 == 128 && KT2 == 64) {
        char* w = (char*)d_ws;
        bf16* Xh = (bf16*)w;            w += szX;
        bf16* Xl = (bf16*)w;            w += szX;
        bf16* Uh = (bf16*)w;            w += szU;
        bf16* Ul = (bf16*)w;            w += szU;
        bf16* Zh = (bf16*)w;            w += szZ;
        bf16* Zl = (bf16*)w;            w += szZ;
        bf16* Vh = (bf16*)w;            w += szV;
        bf16* Vl = (bf16*)w;

        split_ew_tiled<<<dim3(DIN / 32, M / 128), dim3(256), 0, stream>>>(
            X, Xh, Xl, DIN);
        split_tr_tiled<<<dim3(DIN / 32, R / 128), dim3(256), 0, stream>>>(
            U, Uh, Ul, R);
        split_tr_tiled<<<dim3(R / 32, DOUT / 128), dim3(256), 0, stream>>>(
            Zw, Zh, Zl, DOUT);

        qlin_mfma8<1, 128><<<dim3(R / BN, M / BM), dim3(512), 0, stream>>>(
            Xh, Xl, Uh, Ul, M, R, nullptr, Vh, Vl,
            lx, lw, dx, cb, rcb, nullptr);
        qlin_mfma8<2, 64><<<dim3(DOUT / BN, M / BM), dim3(512), 0, stream>>>(
            Vh, Vl, Zh, Zl, M, DOUT, out, nullptr, nullptr,
            nullptr, nullptr, nullptr, nullptr, nullptr, bias);
    } else {
        float* V = (float*)d_ws;
        qlin_mfma<1><<<dim3(R / BN, M / BM), dim3(256), 0, stream>>>(
            X, U, V, M, R, DIN, lx, lw, dx, cb, rcb, nullptr);
        qlin_mfma<2><<<dim3(DOUT / BN, M / BM), dim3(256), 0, stream>>>(
            V, Zw, out, M, DOUT, R, nullptr, nullptr, nullptr, nullptr, nullptr, bias);
    }
}

// Round 16
// 461.169 us; speedup vs baseline: 1.0391x; 1.0391x over previous
//
#include <hip/hip_runtime.h>
#include <math.h>

// R15 measured: REGRESSION 479us (per-GEMM 235, MfmaUtil 39, conflicts
// 0 -> 1.678e7). 32x32 MFMA + old row-major-swizzled tile = 32-row frag
// reads at 128B row stride -> bank pileup. R16: k-chunk-major tile format
// (slot = kc*128 + row) -> each wave frag read = two contiguous 512B runs
// (same shape as gload writes, which measure 0 conflicts). 32x32 stream +
// R14 pipeline (3-buf, vmcnt(6), setprio) kept verbatim. absmax must stay
// exactly 0.0390625 (same accumulation tree as R15).

typedef __bf16 bf16;
typedef bf16 bf16x2 __attribute__((ext_vector_type(2)));
typedef bf16 bf16x4 __attribute__((ext_vector_type(4)));
typedef bf16 bf16x8 __attribute__((ext_vector_type(8)));
typedef float f32x4 __attribute__((ext_vector_type(4)));
typedef float f32x16 __attribute__((ext_vector_type(16)));

#define EPS_Q 1e-8f

constexpr int BM = 128, BN = 128, BK = 32;

__device__ __forceinline__ void gload16(const void* g, void* l) {
    __builtin_amdgcn_global_load_lds(
        (const __attribute__((address_space(1))) unsigned int*)g,
        (__attribute__((address_space(3))) unsigned int*)l, 16, 0, 0);
}

// ---------------------------------------------------------------- prep
// Tile format (8KB per 128x32 bf16 tile): slot = kc*128 + row, 8 bf16/slot.
__global__ __launch_bounds__(256)
void split_ew_tiled(const float* __restrict__ in, bf16* __restrict__ h,
                    bf16* __restrict__ l, int K)
{
    const int t = threadIdx.x;
    #pragma unroll
    for (int i = 0; i < 2; ++i) {
        const int s   = t + i * 256;
        const int row = s >> 2;
        const int kc  = s & 3;
        const float* src = in + (size_t)(blockIdx.y * 128 + row) * K
                              + blockIdx.x * 32 + kc * 8;
        const f32x4 v0 = *reinterpret_cast<const f32x4*>(src);
        const f32x4 v1 = *reinterpret_cast<const f32x4*>(src + 4);
        bf16x8 hh, ll;
        #pragma unroll
        for (int e = 0; e < 4; ++e) {
            const bf16 b0 = (bf16)v0[e];
            hh[e] = b0; ll[e] = (bf16)(v0[e] - (float)b0);
            const bf16 b1 = (bf16)v1[e];
            hh[e + 4] = b1; ll[e + 4] = (bf16)(v1[e] - (float)b1);
        }
        const int slot = kc * 128 + row;
        const size_t base = ((size_t)blockIdx.y * gridDim.x + blockIdx.x) * 4096
                          + slot * 8;
        *reinterpret_cast<bf16x8*>(h + base) = hh;
        *reinterpret_cast<bf16x8*>(l + base) = ll;
    }
}

__global__ __launch_bounds__(256)
void split_tr_tiled(const float* __restrict__ in, bf16* __restrict__ h,
                    bf16* __restrict__ l, int Ncols)
{
    const int t = threadIdx.x;
    #pragma unroll
    for (int i = 0; i < 2; ++i) {
        const int s   = t + i * 256;
        const int kc  = s >> 7;
        const int row = s & 127;
        const int sc  = blockIdx.y * 128 + row;
        const int sr  = blockIdx.x * 32 + kc * 8;
        bf16x8 hh, ll;
        #pragma unroll
        for (int j = 0; j < 8; ++j) {
            const float v = in[(size_t)(sr + j) * Ncols + sc];
            const bf16 b = (bf16)v;
            hh[j] = b; ll[j] = (bf16)(v - (float)b);
        }
        const int slot = kc * 128 + row;
        const size_t base = ((size_t)blockIdx.y * gridDim.x + blockIdx.x) * 4096
                          + slot * 8;
        *reinterpret_cast<bf16x8*>(h + base) = hh;
        *reinterpret_cast<bf16x8*>(l + base) = ll;
    }
}

// ------------------------------------------------------ pipelined GEMM
#define MFMA32(a,b,c) __builtin_amdgcn_mfma_f32_32x32x16_bf16((a),(b),(c),0,0,0)

// fA[set][0]=h,s0  [1]=h,s1  [2]=l,s0  [3]=l,s1
#define LOAD_A(kt, SET)                                                       \
{   const size_t tb_ = (size_t)(kt) * 8192;                                   \
    fA[SET][0] = *reinterpret_cast<const bf16x8*>(pAh + tb_ + offA[0]);       \
    fA[SET][1] = *reinterpret_cast<const bf16x8*>(pAh + tb_ + offA[1]);       \
    fA[SET][2] = *reinterpret_cast<const bf16x8*>(pAl + tb_ + offA[0]);       \
    fA[SET][3] = *reinterpret_cast<const bf16x8*>(pAl + tb_ + offA[1]); }

#define STAGE_B(kt, BUF)                                                      \
{   const size_t tB_ = (tileB0 + (kt)) * 8192;                                \
    gload16((const char*)Bh_g + tB_ + so, (char*)sBh[BUF] + so);              \
    gload16((const char*)Bl_g + tB_ + so, (char*)sBl[BUF] + so); }

// W: 6 = steady, 4 = tail-1, -1 = last (no barrier)
#define BODY(kt, S, W)                                                        \
{                                                                             \
    if ((kt) + 1 < KT) LOAD_A((kt) + 1, ((S) + 1) % 3);                       \
    __builtin_amdgcn_s_setprio(1);                                            \
    {                                                                         \
        bf16x8 bh00 = *reinterpret_cast<const bf16x8*>((const char*)sBh[(S)] + offB[0]); \
        bf16x8 bh01 = *reinterpret_cast<const bf16x8*>((const char*)sBh[(S)] + offB[1]); \
        bf16x8 bh10 = *reinterpret_cast<const bf16x8*>((const char*)sBh[(S)] + offB[2]); \
        bf16x8 bh11 = *reinterpret_cast<const bf16x8*>((const char*)sBh[(S)] + offB[3]); \
        bf16x8 bl00 = *reinterpret_cast<const bf16x8*>((const char*)sBl[(S)] + offB[0]); \
        bf16x8 bl01 = *reinterpret_cast<const bf16x8*>((const char*)sBl[(S)] + offB[1]); \
        bf16x8 bl10 = *reinterpret_cast<const bf16x8*>((const char*)sBl[(S)] + offB[2]); \
        bf16x8 bl11 = *reinterpret_cast<const bf16x8*>((const char*)sBl[(S)] + offB[3]); \
        /* s=0 : pass-major, c inner (adjacent MFMAs independent) */          \
        acc[0] = MFMA32(fA[(S)][0], bh00, acc[0]);                            \
        acc[1] = MFMA32(fA[(S)][0], bh10, acc[1]);                            \
        acc[0] = MFMA32(fA[(S)][0], bl00, acc[0]);                            \
        acc[1] = MFMA32(fA[(S)][0], bl10, acc[1]);                            \
        acc[0] = MFMA32(fA[(S)][2], bh00, acc[0]);                            \
        acc[1] = MFMA32(fA[(S)][2], bh10, acc[1]);                            \
        /* s=1 */                                                             \
        acc[0] = MFMA32(fA[(S)][1], bh01, acc[0]);                            \
        acc[1] = MFMA32(fA[(S)][1], bh11, acc[1]);                            \
        acc[0] = MFMA32(fA[(S)][1], bl01, acc[0]);                            \
        acc[1] = MFMA32(fA[(S)][1], bl11, acc[1]);                            \
        acc[0] = MFMA32(fA[(S)][3], bh01, acc[0]);                            \
        acc[1] = MFMA32(fA[(S)][3], bh11, acc[1]);                            \
    }                                                                         \
    __builtin_amdgcn_s_setprio(0);                                            \
    if ((W) == 6)      asm volatile("s_waitcnt vmcnt(6)" ::: "memory");       \
    else if ((W) == 4) asm volatile("s_waitcnt vmcnt(4)" ::: "memory");       \
    else if ((W) == 0) asm volatile("s_waitcnt vmcnt(0)" ::: "memory");       \
    if ((W) >= 0) {                                                           \
        __builtin_amdgcn_sched_barrier(0);                                    \
        __builtin_amdgcn_s_barrier();                                         \
        __builtin_amdgcn_sched_barrier(0);                                    \
        if ((kt) + 3 < KT) STAGE_B((kt) + 3, (S));                            \
    }                                                                         \
}

template<int EPI, int KT>
__global__ __launch_bounds__(512, 4)
void qlin_mfma9(const bf16* __restrict__ Ah_g, const bf16* __restrict__ Al_g,
                const bf16* __restrict__ Bh_g, const bf16* __restrict__ Bl_g,
                int M, int N,
                float* __restrict__ Cf, bf16* __restrict__ Ch, bf16* __restrict__ Cl,
                const float* __restrict__ g_lx, const float* __restrict__ g_lw,
                const float* __restrict__ g_dx, const float* __restrict__ g_cb,
                const float* __restrict__ g_rcb, const float* __restrict__ g_bias)
{
    __shared__ __align__(16) bf16 sBh[3][4096], sBl[3][4096];   // 48 KB
    __shared__ float s_cb[16], s_rcb[16], s_mid[15], s_rmid[15];

    const int tid = threadIdx.x;
    const int ln  = tid & 63;
    const int wid = tid >> 6;

    if (EPI == 1) {
        if (tid < 16) { s_cb[tid] = g_cb[tid]; s_rcb[tid] = g_rcb[tid]; }
        __syncthreads();
        if (tid < 15) {
            s_mid[tid]  = 0.5f * (s_cb[tid] + s_cb[tid + 1]);
            s_rmid[tid] = 0.5f * (s_rcb[tid] + s_rcb[tid + 1]);
        }
    }

    const int wm = (wid >> 1) * 32;    // wave row base
    const int wn = (wid & 1) * 64;     // wave col base
    const int l5 = ln >> 5;            // which k-half of the sub this lane holds
    const int r31 = ln & 31;

    // k-chunk-major tile: byte offset = (kc*128 + row)*16
    int offA[2];
    #pragma unroll
    for (int s = 0; s < 2; ++s) {
        const int kc = s * 2 + l5;
        offA[s] = (kc * 128 + wm + r31) * 16;
    }
    const char* pAh = (const char*)Ah_g + (size_t)blockIdx.y * KT * 8192;
    const char* pAl = (const char*)Al_g + (size_t)blockIdx.y * KT * 8192;

    const size_t tileB0 = (size_t)blockIdx.x * KT;
    const int so = tid << 4;

    // offB[c*2+s]
    int offB[4];
    #pragma unroll
    for (int c = 0; c < 2; ++c)
        #pragma unroll
        for (int s = 0; s < 2; ++s) {
            const int kc = s * 2 + l5;
            offB[c * 2 + s] = (kc * 128 + wn + c * 32 + r31) * 16;
        }

    bf16x8 fA[3][4];
    f32x16 acc[2] = {};

    // prologue: A(0) + B tiles 0,1,2; confirm A0,B0 (leave 4 in flight)
    LOAD_A(0, 0);
    STAGE_B(0, 0);
    STAGE_B(1, 1);
    STAGE_B(2, 2);
    asm volatile("s_waitcnt vmcnt(4)" ::: "memory");
    __builtin_amdgcn_sched_barrier(0);
    __builtin_amdgcn_s_barrier();
    __builtin_amdgcn_sched_barrier(0);

    constexpr int NB   = (KT - 2) % 3;
    constexpr int MAIN = (KT - 2) - NB;
    for (int kt = 0; kt < MAIN; kt += 3) {
        BODY(kt,     0, 6);
        BODY(kt + 1, 1, 6);
        BODY(kt + 2, 2, 6);
    }
    if constexpr (NB >= 1) { BODY(MAIN,     0, 6); }
    if constexpr (NB >= 2) { BODY(MAIN + 1, 1, 6); }
    { constexpr int S1 = (KT - 2) % 3; BODY(KT - 2, S1, 4); }
    { constexpr int S2 = (KT - 1) % 3; BODY(KT - 1, S2, -1); }

    // ---- epilogue (32x32 C/D: col=lane&31, row=(r&3)+8*(r>>2)+4*(lane>>5))
    if (EPI == 1) {
        float mid[15], rmid[15];
        #pragma unroll
        for (int k = 0; k < 15; ++k) { mid[k] = s_mid[k]; rmid[k] = s_rmid[k]; }
        const int NT = N >> 5;
        #pragma unroll
        for (int c = 0; c < 2; ++c) {
            const int cg = blockIdx.x * BN + wn + c * 32 + r31;
            const float lx = g_lx[cg], lw = g_lw[cg], dx = g_dx[cg];
            const float slx = (fabsf(lx) < EPS_Q) ? EPS_Q : lx;
            const float sdx = (fabsf(dx) < EPS_Q) ? EPS_Q : dx;
            const float ilx = 1.0f / slx, isdx = 1.0f / sdx;
            const float c1 = lx * lw, c2 = dx * lw;
            const int tk = cg >> 5, kc = (cg >> 3) & 3, j = cg & 7;
            #pragma unroll
            for (int r = 0; r < 16; ++r) {
                const float p = acc[c][r];
                const float z = p * ilx;
                int i1 = 0;
                #pragma unroll
                for (int k = 0; k < 15; ++k) i1 += (mid[k] < z) ? 1 : 0;
                const float zq = s_cb[i1];
                const float zr = (p - zq * lx) * isdx;
                int i2 = 0;
                #pragma unroll
                for (int k = 0; k < 15; ++k) i2 += (rmid[k] < zr) ? 1 : 0;
                const float qr = s_rcb[i2];
                const float v  = zq * c1 + qr * c2;
                const bf16  vh = (bf16)v;
                const int rowInTile = wm + (r & 3) + 8 * (r >> 2) + 4 * l5;
                const int slot = kc * 128 + rowInTile;
                const size_t o = ((size_t)blockIdx.y * NT + tk) * 4096
                               + slot * 8 + j;
                Ch[o] = vh;
                Cl[o] = (bf16)(v - (float)vh);
            }
        }
    } else {
        #pragma unroll
        for (int c = 0; c < 2; ++c) {
            const int cg = blockIdx.x * BN + wn + c * 32 + r31;
            const float bv = g_bias[cg];
            #pragma unroll
            for (int r = 0; r < 16; ++r) {
                const int row = blockIdx.y * BM + wm + (r & 3) + 8 * (r >> 2) + 4 * l5;
                Cf[(size_t)row * N + cg] = acc[c][r] + bv;
            }
        }
    }
}

// --------------------------------------------- fallback (R7, validated path)
constexpr int FLDK = BK + 8;

__device__ __forceinline__ bf16x8 ld8(const bf16* p) {
    const bf16x4 a = *reinterpret_cast<const bf16x4*>(p);
    const bf16x4 b = *reinterpret_cast<const bf16x4*>(p + 4);
    return __builtin_shufflevector(a, b, 0, 1, 2, 3, 4, 5, 6, 7);
}
#define MFMA_(a,b,c) __builtin_amdgcn_mfma_f32_16x16x32_bf16((a),(b),(c),0,0,0)

template<int EPI>
__global__ __launch_bounds__(256, 2)
void qlin_mfma(const float* __restrict__ A, const float* __restrict__ B,
               float* __restrict__ C, int M, int N, int K,
               const float* __restrict__ g_lx, const float* __restrict__ g_lw,
               const float* __restrict__ g_dx, const float* __restrict__ g_cb,
               const float* __restrict__ g_rcb, const float* __restrict__ g_bias)
{
    __shared__ bf16 Ah[BM][FLDK], Al[BM][FLDK], Bh[BN][FLDK], Bl[BN][FLDK];
    __shared__ float s_cb[16], s_rcb[16], s_mid[15], s_rmid[15];

    const int tid = threadIdx.x;
    const int bm  = blockIdx.y * BM;
    const int bn  = blockIdx.x * BN;

    if (EPI == 1) {
        if (tid < 16) { s_cb[tid] = g_cb[tid]; s_rcb[tid] = g_rcb[tid]; }
        __syncthreads();
        if (tid < 15) {
            s_mid[tid]  = 0.5f * (s_cb[tid] + s_cb[tid + 1]);
            s_rmid[tid] = 0.5f * (s_rcb[tid] + s_rcb[tid + 1]);
        }
    }

    const int am  = tid >> 1;
    const int ak0 = (tid & 1) * 16;
    const int bk  = (tid >> 4) * 2;
    const int bn0 = (tid & 15) * 8;
    const float* Abase = A + (size_t)(bm + am) * K + ak0;

    f32x4 rA[4], rB[4];
    auto LOADREGS = [&](int kt) {
        const float* ap = Abase + (size_t)kt * BK;
        #pragma unroll
        for (int q = 0; q < 4; ++q)
            rA[q] = *reinterpret_cast<const f32x4*>(ap + q * 4);
        #pragma unroll
        for (int q = 0; q < 4; ++q)
            rB[q] = *reinterpret_cast<const f32x4*>(
                B + (size_t)(kt * BK + bk + (q >> 1)) * N + bn + bn0 + (q & 1) * 4);
    };
    auto WRITELDS = [&]() {
        #pragma unroll
        for (int q = 0; q < 4; ++q) {
            bf16x4 h, l;
            #pragma unroll
            for (int e = 0; e < 4; ++e) {
                const float x = rA[q][e];
                const bf16  hh = (bf16)x;
                h[e] = hh;
                l[e] = (bf16)(x - (float)hh);
            }
            *reinterpret_cast<bf16x4*>(&Ah[am][ak0 + q * 4]) = h;
            *reinterpret_cast<bf16x4*>(&Al[am][ak0 + q * 4]) = l;
        }
        const int js = tid & 7;
        #pragma unroll
        for (int jj = 0; jj < 8; ++jj) {
            const int j = (jj + js) & 7;
            const float x0 = rB[(j >> 2)][j & 3];
            const float x1 = rB[2 + (j >> 2)][j & 3];
            const bf16 h0 = (bf16)x0, h1 = (bf16)x1;
            const bf16 l0 = (bf16)(x0 - (float)h0), l1 = (bf16)(x1 - (float)h1);
            bf16x2 ph = {h0, h1}, pl = {l0, l1};
            *reinterpret_cast<bf16x2*>(&Bh[bn0 + j][bk]) = ph;
            *reinterpret_cast<bf16x2*>(&Bl[bn0 + j][bk]) = pl;
        }
    };

    const int ln  = tid & 63;
    const int wid = tid >> 6;
    const int wm  = (wid >> 1) * 64;
    const int wn  = (wid & 1) * 64;
    const int fr  = ln & 15;
    const int k8  = (ln >> 4) * 8;

    f32x4 acc[4][4] = {};
    const int NK = K / BK;
    LOADREGS(0);
    for (int kt = 0; kt < NK; ++kt) {
        __syncthreads();
        WRITELDS();
        __syncthreads();
        if (kt + 1 < NK) LOADREGS(kt + 1);

        bf16x8 fAh[4], fAl[4];
        #pragma unroll
        for (int mi = 0; mi < 4; ++mi) {
            fAh[mi] = ld8(&Ah[wm + mi * 16 + fr][k8]);
            fAl[mi] = ld8(&Al[wm + mi * 16 + fr][k8]);
        }
        #pragma unroll
        for (int nj = 0; nj < 4; ++nj) {
            const bf16x8 fBh = ld8(&Bh[wn + nj * 16 + fr][k8]);
            const bf16x8 fBl = ld8(&Bl[wn + nj * 16 + fr][k8]);
            #pragma unroll
            for (int mi = 0; mi < 4; ++mi) {
                acc[mi][nj] = MFMA_(fAh[mi], fBh, acc[mi][nj]);
                acc[mi][nj] = MFMA_(fAh[mi], fBl, acc[mi][nj]);
                acc[mi][nj] = MFMA_(fAl[mi], fBh, acc[mi][nj]);
            }
        }
    }

    const int rbase = bm + wm + (ln >> 4) * 4;
    if (EPI == 1) {
        float mid[15], rmid[15];
        #pragma unroll
        for (int k = 0; k < 15; ++k) { mid[k] = s_mid[k]; rmid[k] = s_rmid[k]; }
        #pragma unroll
        for (int nj = 0; nj < 4; ++nj) {
            const int c = bn + wn + nj * 16 + fr;
            const float lx = g_lx[c], lw = g_lw[c], dx = g_dx[c];
            const float slx = (fabsf(lx) < EPS_Q) ? EPS_Q : lx;
            const float sdx = (fabsf(dx) < EPS_Q) ? EPS_Q : dx;
            const float ilx = 1.0f / slx, isdx = 1.0f / sdx;
            const float c1 = lx * lw, c2 = dx * lw;
            #pragma unroll
            for (int mi = 0; mi < 4; ++mi)
                #pragma unroll
                for (int r = 0; r < 4; ++r) {
                    const float p = acc[mi][nj][r];
                    const float z = p * ilx;
                    int i1 = 0;
                    #pragma unroll
                    for (int k = 0; k < 15; ++k) i1 += (mid[k] < z) ? 1 : 0;
                    const float zq = s_cb[i1];
                    const float zr = (p - zq * lx) * isdx;
                    int i2 = 0;
                    #pragma unroll
                    for (int k = 0; k < 15; ++k) i2 += (rmid[k] < zr) ? 1 : 0;
                    const float qr = s_rcb[i2];
                    C[(size_t)(rbase + mi * 16 + r) * N + c] = zq * c1 + qr * c2;
                }
        }
    } else {
        #pragma unroll
        for (int nj = 0; nj < 4; ++nj) {
            const int c = bn + wn + nj * 16 + fr;
            const float bv = g_bias[c];
            #pragma unroll
            for (int mi = 0; mi < 4; ++mi)
                #pragma unroll
                for (int r = 0; r < 4; ++r)
                    C[(size_t)(rbase + mi * 16 + r) * N + c] = acc[mi][nj][r] + bv;
        }
    }
}

// ------------------------------------------------------------------- launch
extern "C" void kernel_launch(void* const* d_in, const int* in_sizes, int n_in,
                              void* d_out, int out_size, void* d_ws, size_t ws_size,
                              hipStream_t stream)
{
    const float* X    = (const float*)d_in[0];
    const float* U    = (const float*)d_in[1];
    const float* lx   = (const float*)d_in[2];
    const float* lw   = (const float*)d_in[3];
    const float* Zw   = (const float*)d_in[4];
    const float* cb   = (const float*)d_in[5];
    const float* dx   = (const float*)d_in[6];
    const float* rcb  = (const float*)d_in[7];
    const float* bias = (const float*)d_in[8];
    float* out = (float*)d_out;

    const int R    = in_sizes[2];
    const int DIN  = in_sizes[1] / R;
    const int M    = in_sizes[0] / DIN;
    const int DOUT = in_sizes[8];

    const size_t szX = (size_t)M * DIN * sizeof(bf16);
    const size_t szU = (size_t)DIN * R * sizeof(bf16);
    const size_t szZ = (size_t)R * DOUT * sizeof(bf16);
    const size_t szV = (size_t)M * R * sizeof(bf16);
    const size_t need = 2 * (szX + szU + szZ + szV);

    const int KT1 = DIN / 32;
    const int KT2 = R / 32;

    if (ws_size >= need && KT1 == 128 && KT2 == 64) {
        char* w = (char*)d_ws;
        bf16* Xh = (bf16*)w;            w += szX;
        bf16* Xl = (bf16*)w;            w += szX;
        bf16* Uh = (bf16*)w;            w += szU;
        bf16* Ul = (bf16*)w;            w += szU;
        bf16* Zh = (bf16*)w;            w += szZ;
        bf16* Zl = (bf16*)w;            w += szZ;
        bf16* Vh = (bf16*)w;            w += szV;
        bf16* Vl = (bf16*)w;

        split_ew_tiled<<<dim3(DIN / 32, M / 128), dim3(256), 0, stream>>>(
            X, Xh, Xl, DIN);
        split_tr_tiled<<<dim3(DIN / 32, R / 128), dim3(256), 0, stream>>>(
            U, Uh, Ul, R);
        split_tr_tiled<<<dim3(R / 32, DOUT / 128), dim3(256), 0, stream>>>(
            Zw, Zh, Zl, DOUT);

        qlin_mfma9<1, 128><<<dim3(R / BN, M / BM), dim3(512), 0, stream>>>(
            Xh, Xl, Uh, Ul, M, R, nullptr, Vh, Vl,
            lx, lw, dx, cb, rcb, nullptr);
        qlin_mfma9<2, 64><<<dim3(DOUT / BN, M / BM), dim3(512), 0, stream>>>(
            Vh, Vl, Zh, Zl, M, DOUT, out, nullptr, nullptr,
            nullptr, nullptr, nullptr, nullptr, nullptr, bias);
    } else {
        float* V = (float*)d_ws;
        qlin_mfma<1><<<dim3(R / BN, M / BM), dim3(256), 0, stream>>>(
            X, U, V, M, R, DIN, lx, lw, dx, cb, rcb, nullptr);
        qlin_mfma<2><<<dim3(DOUT / BN, M / BM), dim3(256), 0, stream>>>(
            V, Zw, out, M, DOUT, R, nullptr, nullptr, nullptr, nullptr, nullptr, bias);
    }
}

// Round 17
// 406.500 us; speedup vs baseline: 1.1788x; 1.1345x over previous
//
#include <hip/hip_runtime.h>
#include <math.h>

// R16 measured: conflicts 0 but 228us/GEMM < R14's 195 -> 32x32's 2 chains
// of 6 dependent MFMAs lose to 16x16's 8 chains of 3 (ILP > inst count).
// R17: revert to 16x16 frags (kc-major tile format kept: contiguous 256B
// runs per 16-lane group = conflict-free for this reader too) + T3 phase
// split: 2 phases/K-step {4 ds_read, 12 MFMA pass-major} | barrier |
// {4 ds_read, 12 MFMA} | vmcnt(6) | barrier | stage. Same per-acc chain
// order (hh->hl->lh) -> bit-identical: absmax must stay 0.0390625.

typedef __bf16 bf16;
typedef bf16 bf16x2 __attribute__((ext_vector_type(2)));
typedef bf16 bf16x4 __attribute__((ext_vector_type(4)));
typedef bf16 bf16x8 __attribute__((ext_vector_type(8)));
typedef float f32x4 __attribute__((ext_vector_type(4)));

#define EPS_Q 1e-8f

constexpr int BM = 128, BN = 128, BK = 32;

__device__ __forceinline__ void gload16(const void* g, void* l) {
    __builtin_amdgcn_global_load_lds(
        (const __attribute__((address_space(1))) unsigned int*)g,
        (__attribute__((address_space(3))) unsigned int*)l, 16, 0, 0);
}

// ---------------------------------------------------------------- prep
// Tile format (8KB per 128x32 bf16 tile): slot = kc*128 + row, 8 bf16/slot.
__global__ __launch_bounds__(256)
void split_ew_tiled(const float* __restrict__ in, bf16* __restrict__ h,
                    bf16* __restrict__ l, int K)
{
    const int t = threadIdx.x;
    #pragma unroll
    for (int i = 0; i < 2; ++i) {
        const int s   = t + i * 256;
        const int row = s >> 2;
        const int kc  = s & 3;
        const float* src = in + (size_t)(blockIdx.y * 128 + row) * K
                              + blockIdx.x * 32 + kc * 8;
        const f32x4 v0 = *reinterpret_cast<const f32x4*>(src);
        const f32x4 v1 = *reinterpret_cast<const f32x4*>(src + 4);
        bf16x8 hh, ll;
        #pragma unroll
        for (int e = 0; e < 4; ++e) {
            const bf16 b0 = (bf16)v0[e];
            hh[e] = b0; ll[e] = (bf16)(v0[e] - (float)b0);
            const bf16 b1 = (bf16)v1[e];
            hh[e + 4] = b1; ll[e + 4] = (bf16)(v1[e] - (float)b1);
        }
        const int slot = kc * 128 + row;
        const size_t base = ((size_t)blockIdx.y * gridDim.x + blockIdx.x) * 4096
                          + slot * 8;
        *reinterpret_cast<bf16x8*>(h + base) = hh;
        *reinterpret_cast<bf16x8*>(l + base) = ll;
    }
}

__global__ __launch_bounds__(256)
void split_tr_tiled(const float* __restrict__ in, bf16* __restrict__ h,
                    bf16* __restrict__ l, int Ncols)
{
    const int t = threadIdx.x;
    #pragma unroll
    for (int i = 0; i < 2; ++i) {
        const int s   = t + i * 256;
        const int kc  = s >> 7;
        const int row = s & 127;
        const int sc  = blockIdx.y * 128 + row;
        const int sr  = blockIdx.x * 32 + kc * 8;
        bf16x8 hh, ll;
        #pragma unroll
        for (int j = 0; j < 8; ++j) {
            const float v = in[(size_t)(sr + j) * Ncols + sc];
            const bf16 b = (bf16)v;
            hh[j] = b; ll[j] = (bf16)(v - (float)b);
        }
        const int slot = kc * 128 + row;
        const size_t base = ((size_t)blockIdx.y * gridDim.x + blockIdx.x) * 4096
                          + slot * 8;
        *reinterpret_cast<bf16x8*>(h + base) = hh;
        *reinterpret_cast<bf16x8*>(l + base) = ll;
    }
}

// ------------------------------------------------------ pipelined GEMM
#define MFMA_(a,b,c) __builtin_amdgcn_mfma_f32_16x16x32_bf16((a),(b),(c),0,0,0)

// fA[set][0]=h,mi0 [1]=h,mi1 [2]=l,mi0 [3]=l,mi1
#define LOAD_A(kt, SET)                                                       \
{   const size_t tb_ = (size_t)(kt) * 8192;                                   \
    fA[SET][0] = *reinterpret_cast<const bf16x8*>(pAh + tb_ + offA[0]);       \
    fA[SET][1] = *reinterpret_cast<const bf16x8*>(pAh + tb_ + offA[1]);       \
    fA[SET][2] = *reinterpret_cast<const bf16x8*>(pAl + tb_ + offA[0]);       \
    fA[SET][3] = *reinterpret_cast<const bf16x8*>(pAl + tb_ + offA[1]); }

#define STAGE_B(kt, BUF)                                                      \
{   const size_t tB_ = (tileB0 + (kt)) * 8192;                                \
    gload16((const char*)Bh_g + tB_ + so, (char*)sBh[BUF] + so);              \
    gload16((const char*)Bl_g + tB_ + so, (char*)sBl[BUF] + so); }

// 12 MFMA over nj pair (J0,J1), pass-major (dependents 4 apart)
#define MFMA_PHASE(S, J0, J1)                                                 \
{   const bf16x8 b0h = *reinterpret_cast<const bf16x8*>((const char*)sBh[(S)] + offB[J0]); \
    const bf16x8 b1h = *reinterpret_cast<const bf16x8*>((const char*)sBh[(S)] + offB[J1]); \
    const bf16x8 b0l = *reinterpret_cast<const bf16x8*>((const char*)sBl[(S)] + offB[J0]); \
    const bf16x8 b1l = *reinterpret_cast<const bf16x8*>((const char*)sBl[(S)] + offB[J1]); \
    __builtin_amdgcn_s_setprio(1);                                            \
    acc[0][J0] = MFMA_(fA[(S)][0], b0h, acc[0][J0]);                          \
    acc[0][J1] = MFMA_(fA[(S)][0], b1h, acc[0][J1]);                          \
    acc[1][J0] = MFMA_(fA[(S)][1], b0h, acc[1][J0]);                          \
    acc[1][J1] = MFMA_(fA[(S)][1], b1h, acc[1][J1]);                          \
    acc[0][J0] = MFMA_(fA[(S)][0], b0l, acc[0][J0]);                          \
    acc[0][J1] = MFMA_(fA[(S)][0], b1l, acc[0][J1]);                          \
    acc[1][J0] = MFMA_(fA[(S)][1], b0l, acc[1][J0]);                          \
    acc[1][J1] = MFMA_(fA[(S)][1], b1l, acc[1][J1]);                          \
    acc[0][J0] = MFMA_(fA[(S)][2], b0h, acc[0][J0]);                          \
    acc[0][J1] = MFMA_(fA[(S)][2], b1h, acc[0][J1]);                          \
    acc[1][J0] = MFMA_(fA[(S)][3], b0h, acc[1][J0]);                          \
    acc[1][J1] = MFMA_(fA[(S)][3], b1h, acc[1][J1]);                          \
    __builtin_amdgcn_s_setprio(0); }

// W: 6 = steady, 4 = tail-1, -1 = last (no trailing wait/barrier/stage)
#define BODY(kt, S, W)                                                        \
{                                                                             \
    /* phase 0 */                                                             \
    if ((kt) + 1 < KT) LOAD_A((kt) + 1, ((S) + 1) % 3);                       \
    MFMA_PHASE(S, 0, 1)                                                       \
    __builtin_amdgcn_s_barrier();                                             \
    /* phase 1 */                                                             \
    MFMA_PHASE(S, 2, 3)                                                       \
    if ((W) == 6)      asm volatile("s_waitcnt vmcnt(6)" ::: "memory");       \
    else if ((W) == 4) asm volatile("s_waitcnt vmcnt(4)" ::: "memory");       \
    else if ((W) == 0) asm volatile("s_waitcnt vmcnt(0)" ::: "memory");       \
    if ((W) >= 0) {                                                           \
        __builtin_amdgcn_sched_barrier(0);                                    \
        __builtin_amdgcn_s_barrier();                                         \
        __builtin_amdgcn_sched_barrier(0);                                    \
        if ((kt) + 3 < KT) STAGE_B((kt) + 3, (S));                            \
    }                                                                         \
}

template<int EPI, int KT>
__global__ __launch_bounds__(512, 4)
void qlin_mfmaA(const bf16* __restrict__ Ah_g, const bf16* __restrict__ Al_g,
                const bf16* __restrict__ Bh_g, const bf16* __restrict__ Bl_g,
                int M, int N,
                float* __restrict__ Cf, bf16* __restrict__ Ch, bf16* __restrict__ Cl,
                const float* __restrict__ g_lx, const float* __restrict__ g_lw,
                const float* __restrict__ g_dx, const float* __restrict__ g_cb,
                const float* __restrict__ g_rcb, const float* __restrict__ g_bias)
{
    __shared__ __align__(16) bf16 sBh[3][4096], sBl[3][4096];   // 48 KB
    __shared__ float s_cb[16], s_rcb[16], s_mid[15], s_rmid[15];

    const int tid = threadIdx.x;
    const int ln  = tid & 63;
    const int wid = tid >> 6;

    if (EPI == 1) {
        if (tid < 16) { s_cb[tid] = g_cb[tid]; s_rcb[tid] = g_rcb[tid]; }
        __syncthreads();
        if (tid < 15) {
            s_mid[tid]  = 0.5f * (s_cb[tid] + s_cb[tid + 1]);
            s_rmid[tid] = 0.5f * (s_rcb[tid] + s_rcb[tid + 1]);
        }
    }

    const int wm = (wid >> 1) * 32;    // wave row base (0,32,64,96)
    const int wn = (wid & 1) * 64;     // wave col base (0,64)
    const int fr = ln & 15;
    const int q  = ln >> 4;            // k-chunk of this lane

    // kc-major tile: byte offset = (kc*128 + row)*16
    int offA[2];
    #pragma unroll
    for (int mi = 0; mi < 2; ++mi)
        offA[mi] = (q * 128 + wm + mi * 16 + fr) * 16;
    const char* pAh = (const char*)Ah_g + (size_t)blockIdx.y * KT * 8192;
    const char* pAl = (const char*)Al_g + (size_t)blockIdx.y * KT * 8192;

    const size_t tileB0 = (size_t)blockIdx.x * KT;
    const int so = tid << 4;

    int offB[4];
    #pragma unroll
    for (int nj = 0; nj < 4; ++nj)
        offB[nj] = (q * 128 + wn + nj * 16 + fr) * 16;

    bf16x8 fA[3][4];
    f32x4 acc[2][4] = {};

    // prologue: A(0) + B tiles 0,1,2; confirm A0,B0 (leave 4 in flight)
    LOAD_A(0, 0);
    STAGE_B(0, 0);
    STAGE_B(1, 1);
    STAGE_B(2, 2);
    asm volatile("s_waitcnt vmcnt(4)" ::: "memory");
    __builtin_amdgcn_sched_barrier(0);
    __builtin_amdgcn_s_barrier();
    __builtin_amdgcn_sched_barrier(0);

    constexpr int NB   = (KT - 2) % 3;
    constexpr int MAIN = (KT - 2) - NB;
    for (int kt = 0; kt < MAIN; kt += 3) {
        BODY(kt,     0, 6);
        BODY(kt + 1, 1, 6);
        BODY(kt + 2, 2, 6);
    }
    if constexpr (NB >= 1) { BODY(MAIN,     0, 6); }
    if constexpr (NB >= 2) { BODY(MAIN + 1, 1, 6); }
    { constexpr int S1 = (KT - 2) % 3; BODY(KT - 2, S1, 4); }
    { constexpr int S2 = (KT - 1) % 3; BODY(KT - 1, S2, -1); }

    // ---- epilogue (16x16 C/D: col=lane&15, row=(lane>>4)*4+reg) ----
    const int rloc = wm + q * 4;
    if (EPI == 1) {
        float mid[15], rmid[15];
        #pragma unroll
        for (int k = 0; k < 15; ++k) { mid[k] = s_mid[k]; rmid[k] = s_rmid[k]; }
        const int NT = N >> 5;
        #pragma unroll
        for (int nj = 0; nj < 4; ++nj) {
            const int c = blockIdx.x * BN + wn + nj * 16 + fr;
            const float lx = g_lx[c], lw = g_lw[c], dx = g_dx[c];
            const float slx = (fabsf(lx) < EPS_Q) ? EPS_Q : lx;
            const float sdx = (fabsf(dx) < EPS_Q) ? EPS_Q : dx;
            const float ilx = 1.0f / slx, isdx = 1.0f / sdx;
            const float c1 = lx * lw, c2 = dx * lw;
            const int tk = c >> 5, kc = (c >> 3) & 3, j = c & 7;
            #pragma unroll
            for (int mi = 0; mi < 2; ++mi)
                #pragma unroll
                for (int r = 0; r < 4; ++r) {
                    const float p = acc[mi][nj][r];
                    const float z = p * ilx;
                    int i1 = 0;
                    #pragma unroll
                    for (int k = 0; k < 15; ++k) i1 += (mid[k] < z) ? 1 : 0;
                    const float zq = s_cb[i1];
                    const float zr = (p - zq * lx) * isdx;
                    int i2 = 0;
                    #pragma unroll
                    for (int k = 0; k < 15; ++k) i2 += (rmid[k] < zr) ? 1 : 0;
                    const float qr = s_rcb[i2];
                    const float v  = zq * c1 + qr * c2;
                    const bf16  vh = (bf16)v;
                    const int rowInTile = rloc + mi * 16 + r;
                    const int slot = kc * 128 + rowInTile;
                    const size_t o = ((size_t)blockIdx.y * NT + tk) * 4096
                                   + slot * 8 + j;
                    Ch[o] = vh;
                    Cl[o] = (bf16)(v - (float)vh);
                }
        }
    } else {
        const int rbase = blockIdx.y * BM + rloc;
        #pragma unroll
        for (int nj = 0; nj < 4; ++nj) {
            const int c = blockIdx.x * BN + wn + nj * 16 + fr;
            const float bv = g_bias[c];
            #pragma unroll
            for (int mi = 0; mi < 2; ++mi)
                #pragma unroll
                for (int r = 0; r < 4; ++r)
                    Cf[(size_t)(rbase + mi * 16 + r) * N + c] = acc[mi][nj][r] + bv;
        }
    }
}

// --------------------------------------------- fallback (R7, validated path)
constexpr int FLDK = BK + 8;

__device__ __forceinline__ bf16x8 ld8(const bf16* p) {
    const bf16x4 a = *reinterpret_cast<const bf16x4*>(p);
    const bf16x4 b = *reinterpret_cast<const bf16x4*>(p + 4);
    return __builtin_shufflevector(a, b, 0, 1, 2, 3, 4, 5, 6, 7);
}

template<int EPI>
__global__ __launch_bounds__(256, 2)
void qlin_mfma(const float* __restrict__ A, const float* __restrict__ B,
               float* __restrict__ C, int M, int N, int K,
               const float* __restrict__ g_lx, const float* __restrict__ g_lw,
               const float* __restrict__ g_dx, const float* __restrict__ g_cb,
               const float* __restrict__ g_rcb, const float* __restrict__ g_bias)
{
    __shared__ bf16 Ah[BM][FLDK], Al[BM][FLDK], Bh[BN][FLDK], Bl[BN][FLDK];
    __shared__ float s_cb[16], s_rcb[16], s_mid[15], s_rmid[15];

    const int tid = threadIdx.x;
    const int bm  = blockIdx.y * BM;
    const int bn  = blockIdx.x * BN;

    if (EPI == 1) {
        if (tid < 16) { s_cb[tid] = g_cb[tid]; s_rcb[tid] = g_rcb[tid]; }
        __syncthreads();
        if (tid < 15) {
            s_mid[tid]  = 0.5f * (s_cb[tid] + s_cb[tid + 1]);
            s_rmid[tid] = 0.5f * (s_rcb[tid] + s_rcb[tid + 1]);
        }
    }

    const int am  = tid >> 1;
    const int ak0 = (tid & 1) * 16;
    const int bk  = (tid >> 4) * 2;
    const int bn0 = (tid & 15) * 8;
    const float* Abase = A + (size_t)(bm + am) * K + ak0;

    f32x4 rA[4], rB[4];
    auto LOADREGS = [&](int kt) {
        const float* ap = Abase + (size_t)kt * BK;
        #pragma unroll
        for (int q = 0; q < 4; ++q)
            rA[q] = *reinterpret_cast<const f32x4*>(ap + q * 4);
        #pragma unroll
        for (int q = 0; q < 4; ++q)
            rB[q] = *reinterpret_cast<const f32x4*>(
                B + (size_t)(kt * BK + bk + (q >> 1)) * N + bn + bn0 + (q & 1) * 4);
    };
    auto WRITELDS = [&]() {
        #pragma unroll
        for (int q = 0; q < 4; ++q) {
            bf16x4 h, l;
            #pragma unroll
            for (int e = 0; e < 4; ++e) {
                const float x = rA[q][e];
                const bf16  hh = (bf16)x;
                h[e] = hh;
                l[e] = (bf16)(x - (float)hh);
            }
            *reinterpret_cast<bf16x4*>(&Ah[am][ak0 + q * 4]) = h;
            *reinterpret_cast<bf16x4*>(&Al[am][ak0 + q * 4]) = l;
        }
        const int js = tid & 7;
        #pragma unroll
        for (int jj = 0; jj < 8; ++jj) {
            const int j = (jj + js) & 7;
            const float x0 = rB[(j >> 2)][j & 3];
            const float x1 = rB[2 + (j >> 2)][j & 3];
            const bf16 h0 = (bf16)x0, h1 = (bf16)x1;
            const bf16 l0 = (bf16)(x0 - (float)h0), l1 = (bf16)(x1 - (float)h1);
            bf16x2 ph = {h0, h1}, pl = {l0, l1};
            *reinterpret_cast<bf16x2*>(&Bh[bn0 + j][bk]) = ph;
            *reinterpret_cast<bf16x2*>(&Bl[bn0 + j][bk]) = pl;
        }
    };

    const int ln  = tid & 63;
    const int wid = tid >> 6;
    const int wm  = (wid >> 1) * 64;
    const int wn  = (wid & 1) * 64;
    const int fr  = ln & 15;
    const int k8  = (ln >> 4) * 8;

    f32x4 acc[4][4] = {};
    const int NK = K / BK;
    LOADREGS(0);
    for (int kt = 0; kt < NK; ++kt) {
        __syncthreads();
        WRITELDS();
        __syncthreads();
        if (kt + 1 < NK) LOADREGS(kt + 1);

        bf16x8 fAh[4], fAl[4];
        #pragma unroll
        for (int mi = 0; mi < 4; ++mi) {
            fAh[mi] = ld8(&Ah[wm + mi * 16 + fr][k8]);
            fAl[mi] = ld8(&Al[wm + mi * 16 + fr][k8]);
        }
        #pragma unroll
        for (int nj = 0; nj < 4; ++nj) {
            const bf16x8 fBh = ld8(&Bh[wn + nj * 16 + fr][k8]);
            const bf16x8 fBl = ld8(&Bl[wn + nj * 16 + fr][k8]);
            #pragma unroll
            for (int mi = 0; mi < 4; ++mi) {
                acc[mi][nj] = MFMA_(fAh[mi], fBh, acc[mi][nj]);
                acc[mi][nj] = MFMA_(fAh[mi], fBl, acc[mi][nj]);
                acc[mi][nj] = MFMA_(fAl[mi], fBh, acc[mi][nj]);
            }
        }
    }

    const int rbase = bm + wm + (ln >> 4) * 4;
    if (EPI == 1) {
        float mid[15], rmid[15];
        #pragma unroll
        for (int k = 0; k < 15; ++k) { mid[k] = s_mid[k]; rmid[k] = s_rmid[k]; }
        #pragma unroll
        for (int nj = 0; nj < 4; ++nj) {
            const int c = bn + wn + nj * 16 + fr;
            const float lx = g_lx[c], lw = g_lw[c], dx = g_dx[c];
            const float slx = (fabsf(lx) < EPS_Q) ? EPS_Q : lx;
            const float sdx = (fabsf(dx) < EPS_Q) ? EPS_Q : dx;
            const float ilx = 1.0f / slx, isdx = 1.0f / sdx;
            const float c1 = lx * lw, c2 = dx * lw;
            #pragma unroll
            for (int mi = 0; mi < 4; ++mi)
                #pragma unroll
                for (int r = 0; r < 4; ++r) {
                    const float p = acc[mi][nj][r];
                    const float z = p * ilx;
                    int i1 = 0;
                    #pragma unroll
                    for (int k = 0; k < 15; ++k) i1 += (mid[k] < z) ? 1 : 0;
                    const float zq = s_cb[i1];
                    const float zr = (p - zq * lx) * isdx;
                    int i2 = 0;
                    #pragma unroll
                    for (int k = 0; k < 15; ++k) i2 += (rmid[k] < zr) ? 1 : 0;
                    const float qr = s_rcb[i2];
                    C[(size_t)(rbase + mi * 16 + r) * N + c] = zq * c1 + qr * c2;
                }
        }
    } else {
        #pragma unroll
        for (int nj = 0; nj < 4; ++nj) {
            const int c = bn + wn + nj * 16 + fr;
            const float bv = g_bias[c];
            #pragma unroll
            for (int mi = 0; mi < 4; ++mi)
                #pragma unroll
                for (int r = 0; r < 4; ++r)
                    C[(size_t)(rbase + mi * 16 + r) * N + c] = acc[mi][nj][r] + bv;
        }
    }
}

// ------------------------------------------------------------------- launch
extern "C" void kernel_launch(void* const* d_in, const int* in_sizes, int n_in,
                              void* d_out, int out_size, void* d_ws, size_t ws_size,
                              hipStream_t stream)
{
    const float* X    = (const float*)d_in[0];
    const float* U    = (const float*)d_in[1];
    const float* lx   = (const float*)d_in[2];
    const float* lw   = (const float*)d_in[3];
    const float* Zw   = (const float*)d_in[4];
    const float* cb   = (const float*)d_in[5];
    const float* dx   = (const float*)d_in[6];
    const float* rcb  = (const float*)d_in[7];
    const float* bias = (const float*)d_in[8];
    float* out = (float*)d_out;

    const int R    = in_sizes[2];
    const int DIN  = in_sizes[1] / R;
    const int M    = in_sizes[0] / DIN;
    const int DOUT = in_sizes[8];

    const size_t szX = (size_t)M * DIN * sizeof(bf16);
    const size_t szU = (size_t)DIN * R * sizeof(bf16);
    const size_t szZ = (size_t)R * DOUT * sizeof(bf16);
    const size_t szV = (size_t)M * R * sizeof(bf16);
    const size_t need = 2 * (szX + szU + szZ + szV);

    const int KT1 = DIN / 32;
    const int KT2 = R / 32;

    if (ws_size >= need && KT1 == 128 && KT2 == 64) {
        char* w = (char*)d_ws;
        bf16* Xh = (bf16*)w;            w += szX;
        bf16* Xl = (bf16*)w;            w += szX;
        bf16* Uh = (bf16*)w;            w += szU;
        bf16* Ul = (bf16*)w;            w += szU;
        bf16* Zh = (bf16*)w;            w += szZ;
        bf16* Zl = (bf16*)w;            w += szZ;
        bf16* Vh = (bf16*)w;            w += szV;
        bf16* Vl = (bf16*)w;

        split_ew_tiled<<<dim3(DIN / 32, M / 128), dim3(256), 0, stream>>>(
            X, Xh, Xl, DIN);
        split_tr_tiled<<<dim3(DIN / 32, R / 128), dim3(256), 0, stream>>>(
            U, Uh, Ul, R);
        split_tr_tiled<<<dim3(R / 32, DOUT / 128), dim3(256), 0, stream>>>(
            Zw, Zh, Zl, DOUT);

        qlin_mfmaA<1, 128><<<dim3(R / BN, M / BM), dim3(512), 0, stream>>>(
            Xh, Xl, Uh, Ul, M, R, nullptr, Vh, Vl,
            lx, lw, dx, cb, rcb, nullptr);
        qlin_mfmaA<2, 64><<<dim3(DOUT / BN, M / BM), dim3(512), 0, stream>>>(
            Vh, Vl, Zh, Zl, M, DOUT, out, nullptr, nullptr,
            nullptr, nullptr, nullptr, nullptr, nullptr, bias);
    } else {
        float* V = (float*)d_ws;
        qlin_mfma<1><<<dim3(R / BN, M / BM), dim3(256), 0, stream>>>(
            X, U, V, M, R, DIN, lx, lw, dx, cb, rcb, nullptr);
        qlin_mfma<2><<<dim3(DOUT / BN, M / BM), dim3(256), 0, stream>>>(
            V, Zw, out, M, DOUT, R, nullptr, nullptr, nullptr, nullptr, nullptr, bias);
    }
}